// Round 1
// baseline (547.457 us; speedup 1.0000x reference)
//
#include <hip/hip_runtime.h>
#include <hip/hip_fp16.h>

// Problem dims (fixed by reference)
#define S_LEN 1024
#define BSZ   32
#define IN_DIM 1024
#define HID   1024
#define MDIM  (S_LEN*BSZ)   // 32768 GEMM rows
#define NDIM  (2*HID)       // 2048 GEMM cols (z | f stacked)
#define KDIM  IN_DIM        // 1024

typedef __attribute__((ext_vector_type(8))) _Float16 half8;
typedef __attribute__((ext_vector_type(4))) float    floatx4;

// ---------------- fp32 -> fp16 conversion ----------------
__global__ void cvt_x_kernel(const float* __restrict__ x, _Float16* __restrict__ xh) {
    int idx = blockIdx.x * blockDim.x + threadIdx.x;   // one half8 (8 elems) per thread
    const float4* src = (const float4*)x + (size_t)idx * 2;
    float4 a = src[0], b = src[1];
    half8 h;
    h[0] = (_Float16)a.x; h[1] = (_Float16)a.y; h[2] = (_Float16)a.z; h[3] = (_Float16)a.w;
    h[4] = (_Float16)b.x; h[5] = (_Float16)b.y; h[6] = (_Float16)b.z; h[7] = (_Float16)b.w;
    *((half8*)xh + idx) = h;
}

// W = [wm_z ; wm_f] -> [2048][1024] fp16, row-major
__global__ void cvt_w_kernel(const float* __restrict__ wz, const float* __restrict__ wf,
                             _Float16* __restrict__ wh) {
    int idx = blockIdx.x * blockDim.x + threadIdx.x;   // one half8 per thread
    int e0 = idx * 8;
    int row = e0 >> 10;                                 // 0..2047 (8 elems stay in one row)
    const float* src = (row < HID) ? (wz + e0) : (wf + (e0 - HID * KDIM));
    const float4* s4 = (const float4*)src;
    float4 a = s4[0], b = s4[1];
    half8 h;
    h[0] = (_Float16)a.x; h[1] = (_Float16)a.y; h[2] = (_Float16)a.z; h[3] = (_Float16)a.w;
    h[4] = (_Float16)b.x; h[5] = (_Float16)b.y; h[6] = (_Float16)b.z; h[7] = (_Float16)b.w;
    *((half8*)wh + idx) = h;
}

// ---------------- fp16 MFMA GEMM: C[m][n] = sum_k A[m][k] * W[n][k] ----------------
// A: [32768][1024] fp16, W: [2048][1024] fp16.
// n < 1024 -> Cz (d_out), n >= 1024 -> Cf (ws). Both row-major [32768][1024] fp32.
#define BM 128
#define BN 128
#define BK 32

__global__ void gemm_f16_kernel(const _Float16* __restrict__ A, const _Float16* __restrict__ B,
                                float* __restrict__ Cz, float* __restrict__ Cf) {
    __shared__ _Float16 As[BM * BK];   // row-major, row stride BK (64B) — layout forced by global_load_lds
    __shared__ _Float16 Bs[BN * BK];

    const int tid  = threadIdx.x;
    const int lane = tid & 63;
    const int wv   = tid >> 6;          // wave 0..3
    const int tile_n = blockIdx.x;      // 0..15
    const int tile_m = blockIdx.y;      // 0..255
    const int m0  = tile_m * BM;
    const int n0g = tile_n * BN;

    const int wm = (wv >> 1) * 64;      // wave's 64x64 quadrant
    const int wn = (wv & 1) * 64;

    floatx4 acc[4][4] = {};

    const int fr = lane & 15;           // fragment row within 16
    const int fk = (lane >> 4) * 8;     // fragment k offset

    for (int k0 = 0; k0 < KDIM; k0 += BK) {
        // stage A tile (128x32) and B tile (128x32) via async global->LDS, 16B/lane
        #pragma unroll
        for (int i = 0; i < 2; ++i) {
            int cb  = i * 256 + wv * 64;       // wave-uniform chunk base
            int c   = cb + lane;
            int row = c >> 2;
            int kc  = (c & 3) * 8;
            const _Float16* gp = A + (size_t)(m0 + row) * KDIM + k0 + kc;
            __builtin_amdgcn_global_load_lds(
                (const __attribute__((address_space(1))) void*)gp,
                (__attribute__((address_space(3))) void*)(As + (size_t)cb * 8), 16, 0, 0);
            const _Float16* gq = B + (size_t)(n0g + row) * KDIM + k0 + kc;
            __builtin_amdgcn_global_load_lds(
                (const __attribute__((address_space(1))) void*)gq,
                (__attribute__((address_space(3))) void*)(Bs + (size_t)cb * 8), 16, 0, 0);
        }
        __syncthreads();

        half8 af[4], bf[4];
        #pragma unroll
        for (int i = 0; i < 4; ++i)
            af[i] = *(const half8*)(As + (wm + i * 16 + fr) * BK + fk);
        #pragma unroll
        for (int j = 0; j < 4; ++j)
            bf[j] = *(const half8*)(Bs + (wn + j * 16 + fr) * BK + fk);

        #pragma unroll
        for (int i = 0; i < 4; ++i)
            #pragma unroll
            for (int j = 0; j < 4; ++j)
                acc[i][j] = __builtin_amdgcn_mfma_f32_16x16x32_f16(af[i], bf[j], acc[i][j], 0, 0, 0);
        __syncthreads();
    }

    // epilogue: C/D layout col=lane&15, row=(lane>>4)*4+reg  [measured m89/m91]
    float* Cbase;
    int ncol0;
    if (tile_n < 8) { Cbase = Cz; ncol0 = n0g; }
    else            { Cbase = Cf; ncol0 = n0g - HID; }
    const int orow = (lane >> 4) * 4;
    const int ocol = lane & 15;
    #pragma unroll
    for (int i = 0; i < 4; ++i)
        #pragma unroll
        for (int j = 0; j < 4; ++j)
            #pragma unroll
            for (int r = 0; r < 4; ++r) {
                int row = m0 + wm + i * 16 + orow + r;
                int col = ncol0 + wn + j * 16 + ocol;
                Cbase[(size_t)row * HID + col] = acc[i][j][r];
            }
}

// ---------------- sequential scan over s, one thread per (b,h) ----------------
// outz (= d_out) holds pre-activation z in, final cells out (in-place).
#define UNR 8
__global__ __launch_bounds__(64) void scan_kernel(
    float* __restrict__ outz, const float* __restrict__ outf,
    const float* __restrict__ state,
    const float* __restrict__ wvz, const float* __restrict__ wvf,
    const float* __restrict__ bz, const float* __restrict__ bfv) {
    const int t = blockIdx.x * 64 + threadIdx.x;   // 0..32767
    const int h = t & (HID - 1);
    const int stride = BSZ * HID;                  // 32768 floats between timesteps

    float cell = state[t];
    const float az = wvz[h], afc = wvf[h], cz = bz[h], cf = bfv[h];

    float* pz = outz + t;
    const float* pf = outf + t;

    float zv[UNR], fv[UNR];
    #pragma unroll
    for (int u = 0; u < UNR; ++u) {
        zv[u] = pz[(size_t)u * stride];
        fv[u] = pf[(size_t)u * stride];
    }

    for (int s0 = 0; s0 < S_LEN; s0 += UNR) {
        float zn[UNR], fn[UNR];
        if (s0 + UNR < S_LEN) {
            #pragma unroll
            for (int u = 0; u < UNR; ++u) {
                zn[u] = pz[(size_t)(s0 + UNR + u) * stride];
                fn[u] = pf[(size_t)(s0 + UNR + u) * stride];
            }
        }
        #pragma unroll
        for (int u = 0; u < UNR; ++u) {
            float zpre = zv[u] + az * cell + cz;
            float fpre = fv[u] + afc * cell + cf;
            zpre = fminf(fmaxf(zpre, -30.f), 30.f);
            fpre = fminf(fmaxf(fpre, -30.f), 30.f);
            float ez = __expf(2.0f * zpre);
            float zp = (ez - 1.0f) * __builtin_amdgcn_rcpf(ez + 1.0f);   // tanh
            float ef = __expf(-fpre);
            float fp = __builtin_amdgcn_rcpf(1.0f + ef);                 // sigmoid
            cell = cell * fp + (1.0f - fp) * zp;
            pz[(size_t)(s0 + u) * stride] = cell;
        }
        #pragma unroll
        for (int u = 0; u < UNR; ++u) { zv[u] = zn[u]; fv[u] = fn[u]; }
    }
}

extern "C" void kernel_launch(void* const* d_in, const int* in_sizes, int n_in,
                              void* d_out, int out_size, void* d_ws, size_t ws_size,
                              hipStream_t stream) {
    const float* x      = (const float*)d_in[0];
    const float* state  = (const float*)d_in[1];
    const float* wm_z   = (const float*)d_in[2];
    const float* wm_f   = (const float*)d_in[3];
    const float* wv_z   = (const float*)d_in[4];
    const float* wv_f   = (const float*)d_in[5];
    const float* bias_z = (const float*)d_in[6];
    const float* bias_f = (const float*)d_in[7];
    float* out = (float*)d_out;

    // workspace layout: xh 64MB | wh 4MB | out_f 128MB  (total 196MB)
    char* ws = (char*)d_ws;
    _Float16* xh = (_Float16*)ws;
    _Float16* wh = (_Float16*)(ws + (size_t)MDIM * KDIM * sizeof(_Float16));
    float* outf  = (float*)(ws + (size_t)MDIM * KDIM * sizeof(_Float16)
                               + (size_t)NDIM * KDIM * sizeof(_Float16));

    // 1) convert inputs to fp16
    cvt_x_kernel<<<(MDIM * KDIM) / (256 * 8), 256, 0, stream>>>(x, xh);
    cvt_w_kernel<<<(NDIM * KDIM) / (256 * 8), 256, 0, stream>>>(wm_z, wm_f, wh);

    // 2) fused z|f projection GEMM: out_z -> d_out (scratch), out_f -> ws
    dim3 ggrid(NDIM / BN, MDIM / BM);   // (16, 256)
    gemm_f16_kernel<<<ggrid, 256, 0, stream>>>(xh, wh, out, outf);

    // 3) recurrence, overwrites d_out in place
    scan_kernel<<<MDIM / 64, 64, 0, stream>>>(out, outf, state, wv_z, wv_f, bias_z, bias_f);
}

// Round 2
// 455.005 us; speedup vs baseline: 1.2032x; 1.2032x over previous
//
#include <hip/hip_runtime.h>
#include <hip/hip_fp16.h>

// Problem dims (fixed by reference)
#define S_LEN 1024
#define BSZ   32
#define IN_DIM 1024
#define HID   1024
#define MDIM  (S_LEN*BSZ)   // 32768 GEMM rows
#define NDIM  (2*HID)       // 2048 GEMM cols (z | f interleaved in 16-row groups)
#define KDIM  IN_DIM        // 1024

typedef __attribute__((ext_vector_type(8))) _Float16 half8;
typedef __attribute__((ext_vector_type(2))) _Float16 half2v;
typedef __attribute__((ext_vector_type(4))) float    floatx4;

// ---------------- fp32 -> fp16 conversion ----------------
__global__ void cvt_x_kernel(const float* __restrict__ x, _Float16* __restrict__ xh) {
    int idx = blockIdx.x * blockDim.x + threadIdx.x;   // one half8 (8 elems) per thread
    const float4* src = (const float4*)x + (size_t)idx * 2;
    float4 a = src[0], b = src[1];
    half8 h;
    h[0] = (_Float16)a.x; h[1] = (_Float16)a.y; h[2] = (_Float16)a.z; h[3] = (_Float16)a.w;
    h[4] = (_Float16)b.x; h[5] = (_Float16)b.y; h[6] = (_Float16)b.z; h[7] = (_Float16)b.w;
    *((half8*)xh + idx) = h;
}

// Interleaved weight layout: out row r (0..2047): g=r>>5, sub=r&31.
// sub<16 -> wm_z row g*16+sub ; sub>=16 -> wm_f row g*16+(sub-16).
// This makes each 32-row span = [16 z-rows | 16 f-rows] for the same h-group,
// so adjacent 16-col MFMA tiles in the GEMM hold z and f for the same h.
__global__ void cvt_w_kernel(const float* __restrict__ wz, const float* __restrict__ wf,
                             _Float16* __restrict__ wh) {
    int idx = blockIdx.x * blockDim.x + threadIdx.x;   // one half8 per thread
    int e0 = idx * 8;
    int r   = e0 >> 10;        // output row 0..2047
    int col = e0 & 1023;
    int g = r >> 5, sub = r & 31;
    const float* src = (sub < 16)
        ? wz + ((size_t)(g * 16 + sub)      * KDIM + col)
        : wf + ((size_t)(g * 16 + sub - 16) * KDIM + col);
    const float4* s4 = (const float4*)src;
    float4 a = s4[0], b = s4[1];
    half8 h;
    h[0] = (_Float16)a.x; h[1] = (_Float16)a.y; h[2] = (_Float16)a.z; h[3] = (_Float16)a.w;
    h[4] = (_Float16)b.x; h[5] = (_Float16)b.y; h[6] = (_Float16)b.z; h[7] = (_Float16)b.w;
    *((half8*)wh + idx) = h;
}

// ---------------- fp16 MFMA GEMM: zf[m][h] = pack(z, f) fp16x2 ----------------
#define BM 128
#define BN 128
#define BK 32

__global__ void gemm_f16_kernel(const _Float16* __restrict__ A, const _Float16* __restrict__ B,
                                uint* __restrict__ zf) {
    __shared__ _Float16 As[BM * BK];   // row-major, row stride BK — layout forced by global_load_lds
    __shared__ _Float16 Bs[BN * BK];

    const int tid  = threadIdx.x;
    const int lane = tid & 63;
    const int wv   = tid >> 6;          // wave 0..3

    // XCD-aware swizzle: xcd = flat&7 owns whole m-tiles; n iterates fastest
    // within an XCD so one A m-tile is fetched ~once per chip.
    const int flat   = blockIdx.x;      // 0..4095
    const int xcd    = flat & 7;
    const int local  = flat >> 3;       // 0..511
    const int tile_m = (local >> 4) * 8 + xcd;   // 0..255
    const int tile_n = local & 15;               // 0..15
    const int m0  = tile_m * BM;
    const int n0g = tile_n * BN;

    const int wm = (wv >> 1) * 64;      // wave's 64x64 quadrant
    const int wn = (wv & 1) * 64;

    floatx4 acc[4][4] = {};

    const int fr = lane & 15;           // fragment row within 16
    const int fk = (lane >> 4) * 8;     // fragment k offset

    for (int k0 = 0; k0 < KDIM; k0 += BK) {
        #pragma unroll
        for (int i = 0; i < 2; ++i) {
            int cb  = i * 256 + wv * 64;       // wave-uniform chunk base
            int c   = cb + lane;
            int row = c >> 2;
            int kc  = (c & 3) * 8;
            const _Float16* gp = A + (size_t)(m0 + row) * KDIM + k0 + kc;
            __builtin_amdgcn_global_load_lds(
                (const __attribute__((address_space(1))) void*)gp,
                (__attribute__((address_space(3))) void*)(As + (size_t)cb * 8), 16, 0, 0);
            const _Float16* gq = B + (size_t)(n0g + row) * KDIM + k0 + kc;
            __builtin_amdgcn_global_load_lds(
                (const __attribute__((address_space(1))) void*)gq,
                (__attribute__((address_space(3))) void*)(Bs + (size_t)cb * 8), 16, 0, 0);
        }
        __syncthreads();

        half8 af[4], bf[4];
        #pragma unroll
        for (int i = 0; i < 4; ++i)
            af[i] = *(const half8*)(As + (wm + i * 16 + fr) * BK + fk);
        #pragma unroll
        for (int j = 0; j < 4; ++j)
            bf[j] = *(const half8*)(Bs + (wn + j * 16 + fr) * BK + fk);

        #pragma unroll
        for (int i = 0; i < 4; ++i)
            #pragma unroll
            for (int j = 0; j < 4; ++j)
                acc[i][j] = __builtin_amdgcn_mfma_f32_16x16x32_f16(af[i], bf[j], acc[i][j], 0, 0, 0);
        __syncthreads();
    }

    // epilogue: C/D layout col=lane&15, row=(lane>>4)*4+reg  [measured m89/m91]
    // col-tile pair (2p, 2p+1) = (z, f) for h = ((n0g+wn)>>5 + p)*16 + ocol
    const int orow  = (lane >> 4) * 4;
    const int ocol  = lane & 15;
    const int gbase = (n0g + wn) >> 5;
    #pragma unroll
    for (int i = 0; i < 4; ++i)
        #pragma unroll
        for (int p = 0; p < 2; ++p) {
            int h = (gbase + p) * 16 + ocol;
            #pragma unroll
            for (int r = 0; r < 4; ++r) {
                int row = m0 + wm + i * 16 + orow + r;
                half2v v;
                v[0] = (_Float16)acc[i][2 * p][r];       // z
                v[1] = (_Float16)acc[i][2 * p + 1][r];   // f
                *(half2v*)(zf + (size_t)row * HID + h) = v;
            }
        }
}

// ---------------- sequential scan over s, one thread per (b,h) ----------------
#define UNR 32
__global__ __launch_bounds__(64) void scan_kernel(
    const uint* __restrict__ zf, float* __restrict__ out,
    const float* __restrict__ state,
    const float* __restrict__ wvz, const float* __restrict__ wvf,
    const float* __restrict__ bz, const float* __restrict__ bfv) {
    const int t = blockIdx.x * 64 + threadIdx.x;   // 0..32767
    const int h = t & (HID - 1);
    const int stride = BSZ * HID;                  // 32768 elements between timesteps

    float cell = state[t];
    const float az = wvz[h], afc = wvf[h], cz = bz[h], cf = bfv[h];

    const uint* p = zf + t;
    float* po = out + t;

    uint buf[UNR];
    #pragma unroll
    for (int u = 0; u < UNR; ++u) buf[u] = p[(size_t)u * stride];

    for (int s0 = 0; s0 < S_LEN; s0 += UNR) {
        uint nb[UNR];
        if (s0 + UNR < S_LEN) {
            #pragma unroll
            for (int u = 0; u < UNR; ++u)
                nb[u] = p[(size_t)(s0 + UNR + u) * stride];
        }
        #pragma unroll
        for (int u = 0; u < UNR; ++u) {
            half2v h2 = __builtin_bit_cast(half2v, buf[u]);
            float zpre = (float)h2[0] + az * cell + cz;
            float fpre = (float)h2[1] + afc * cell + cf;
            // tanh / sigmoid via exp; no clamps needed: |pre| <= ~30 -> no overflow
            float ez = __expf(2.0f * zpre);
            float zp = (ez - 1.0f) * __builtin_amdgcn_rcpf(ez + 1.0f);
            float fp = __builtin_amdgcn_rcpf(1.0f + __expf(-fpre));
            cell = fmaf(cell - zp, fp, zp);        // cell*fp + (1-fp)*zp
            po[(size_t)(s0 + u) * stride] = cell;
        }
        #pragma unroll
        for (int u = 0; u < UNR; ++u) buf[u] = nb[u];
    }
}

extern "C" void kernel_launch(void* const* d_in, const int* in_sizes, int n_in,
                              void* d_out, int out_size, void* d_ws, size_t ws_size,
                              hipStream_t stream) {
    const float* x      = (const float*)d_in[0];
    const float* state  = (const float*)d_in[1];
    const float* wm_z   = (const float*)d_in[2];
    const float* wm_f   = (const float*)d_in[3];
    const float* wv_z   = (const float*)d_in[4];
    const float* wv_f   = (const float*)d_in[5];
    const float* bias_z = (const float*)d_in[6];
    const float* bias_f = (const float*)d_in[7];
    float* out = (float*)d_out;

    // workspace layout: xh 64MB | wh 4MB | zf 128MB  (total 196MB)
    char* ws = (char*)d_ws;
    _Float16* xh = (_Float16*)ws;
    _Float16* wh = (_Float16*)(ws + (size_t)MDIM * KDIM * sizeof(_Float16));
    uint* zf     = (uint*)(ws + (size_t)MDIM * KDIM * sizeof(_Float16)
                              + (size_t)NDIM * KDIM * sizeof(_Float16));

    // 1) convert inputs to fp16 (weights interleaved z|f in 16-row groups)
    cvt_x_kernel<<<(MDIM * KDIM) / (256 * 8), 256, 0, stream>>>(x, xh);
    cvt_w_kernel<<<(NDIM * KDIM) / (256 * 8), 256, 0, stream>>>(wm_z, wm_f, wh);

    // 2) fused z|f projection GEMM -> interleaved fp16 pre-activations
    gemm_f16_kernel<<<(MDIM / BM) * (NDIM / BN), 256, 0, stream>>>(xh, wh, zf);

    // 3) recurrence -> fp32 output
    scan_kernel<<<MDIM / 64, 64, 0, stream>>>(zf, out, state, wv_z, wv_f, bias_z, bias_f);
}